// Round 11
// baseline (818.250 us; speedup 1.0000x reference)
//
#include <hip/hip_runtime.h>
#include <math.h>

#define N_NODE 100000
#define EMB    100
#define BATCH  512
#define SEQ    50
#define NNZ    1000000

#define SCAN_CHUNK 1024
#define SCAN_NB ((N_NODE + SCAN_CHUNK - 1) / SCAN_CHUNK)   // 98

static __device__ __forceinline__ float bf2f(unsigned short u) {
  union { unsigned int i; float f; } v; v.i = ((unsigned int)u) << 16; return v.f;
}
static __device__ __forceinline__ unsigned short f2bf(float f) {
  union { float f; unsigned int i; } v; v.f = f;
  unsigned int i = v.i;
  return (unsigned short)((i + 0x7fffu + ((i >> 16) & 1u)) >> 16);  // RNE
}
static __device__ __forceinline__ float lo2f(unsigned int u) {
  union { unsigned int i; float f; } v; v.i = u << 16; return v.f;
}
static __device__ __forceinline__ float hi2f(unsigned int u) {
  union { unsigned int i; float f; } v; v.i = u & 0xffff0000u; return v.f;
}
static __device__ __forceinline__ unsigned int packbf2(float x, float y) {
  return (unsigned int)f2bf(x) | ((unsigned int)f2bf(y) << 16);
}

// ---------------- CSR build ----------------
__global__ void hist_kernel(const int* __restrict__ rows, int* __restrict__ counts) {
  int i = blockIdx.x * blockDim.x + threadIdx.x;
  if (i < NNZ) atomicAdd(&counts[rows[i]], 1);
}

// ---- multi-block two-level exclusive scan ----
__global__ void scan_partial_kernel(const int* __restrict__ counts, int* __restrict__ partial) {
  __shared__ int red[256];
  int b = blockIdx.x, t = threadIdx.x;
  int base = b * SCAN_CHUNK;
  int s = 0;
  #pragma unroll
  for (int k = 0; k < SCAN_CHUNK; k += 256) {
    int idx = base + k + t;
    if (idx < N_NODE) s += counts[idx];
  }
  red[t] = s;
  __syncthreads();
  for (int off = 128; off; off >>= 1) {
    if (t < off) red[t] += red[t + off];
    __syncthreads();
  }
  if (t == 0) partial[b] = red[0];
}

__global__ void scan_top_kernel(int* __restrict__ partial, int* __restrict__ row_ptr) {
  __shared__ int s[128];
  int t = threadIdx.x;                    // 128 threads, 1 block
  int v = (t < SCAN_NB) ? partial[t] : 0;
  s[t] = v;
  __syncthreads();
  for (int off = 1; off < 128; off <<= 1) {
    int u = (t >= off) ? s[t - off] : 0;
    __syncthreads();
    s[t] += u;
    __syncthreads();
  }
  if (t < SCAN_NB) partial[t] = (t == 0) ? 0 : s[t - 1];   // exclusive block offsets
  if (t == 127) row_ptr[N_NODE] = s[127];                  // total nnz
}

__global__ void scan_final_kernel(const int* __restrict__ partial,
                                  int* __restrict__ counts_cursor,
                                  int* __restrict__ row_ptr) {
  __shared__ int s[256];
  int b = blockIdx.x, t = threadIdx.x;
  int base = b * SCAN_CHUNK + t * 4;
  int c[4];
  #pragma unroll
  for (int k = 0; k < 4; ++k) {
    int idx = base + k;
    c[k] = (idx < N_NODE) ? counts_cursor[idx] : 0;
  }
  int local = c[0] + c[1] + c[2] + c[3];
  s[t] = local;
  __syncthreads();
  for (int off = 1; off < 256; off <<= 1) {
    int u = (t >= off) ? s[t - off] : 0;
    __syncthreads();
    s[t] += u;
    __syncthreads();
  }
  int prefix = partial[b] + ((t == 0) ? 0 : s[t - 1]);
  #pragma unroll
  for (int k = 0; k < 4; ++k) {
    int idx = base + k;
    if (idx < N_NODE) {
      row_ptr[idx] = prefix;
      counts_cursor[idx] = prefix;
      prefix += c[k];
    }
  }
}

// Tier A: packed CSR, one u32 per nnz: (col<<15) | q15, q15 = round(v*327670)
__global__ void scatterA_kernel(const int* __restrict__ rows, const int* __restrict__ cols,
                                const float* __restrict__ vals, int* __restrict__ cursor,
                                unsigned int* __restrict__ cv) {
  int i = blockIdx.x * blockDim.x + threadIdx.x;
  if (i >= NNZ) return;
  int p = atomicAdd(&cursor[rows[i]], 1);
  int q = (int)rintf(vals[i] * 327670.f);
  q = q < 0 ? 0 : (q > 32767 ? 32767 : q);
  cv[p] = ((unsigned int)cols[i] << 15) | (unsigned int)q;
}

// Tier B: colHi=col>>1 (u16); colLo=(col&1)<<7 | q7, q7=round(v*1270) (err <= 4e-4)
__global__ void scatterB_kernel(const int* __restrict__ rows, const int* __restrict__ cols,
                                const float* __restrict__ vals, int* __restrict__ cursor,
                                unsigned short* __restrict__ colHi, unsigned char* __restrict__ colLo) {
  int i = blockIdx.x * blockDim.x + threadIdx.x;
  if (i >= NNZ) return;
  int p = atomicAdd(&cursor[rows[i]], 1);
  int c = cols[i];
  int q = (int)rintf(vals[i] * 1270.f);
  q = q < 0 ? 0 : (q > 127 ? 127 : q);
  colHi[p] = (unsigned short)(c >> 1);
  colLo[p] = (unsigned char)(((c & 1) << 7) | q);
}

// ---------------- bf16 gather-table build: ebf[i] = packed bf16 pair of emb2[i] ----
__global__ void packbf_kernel(const float2* __restrict__ src, unsigned int* __restrict__ dst) {
  int i = blockIdx.x * blockDim.x + threadIdx.x;
  if (i < N_NODE * 50) {
    float2 v = src[i];
    dst[i] = packbf2(v.x, v.y);
  }
}

// ---------------- packed session weight tables (global, L1-resident in sess) ----------
// w1pG[kp*EMB+e] = bf16 pair (w1_bot[2kp][e], w1_bot[2kp+1][e])
// g1pG[kp*EMB+e] = bf16 pair (glu1w^T[2kp][e], glu1w^T[2kp+1][e]) = glu1w[e][2kp..2kp+1]
__global__ void packw_kernel(const float* __restrict__ w1, const float* __restrict__ glu1w,
                             unsigned int* __restrict__ w1pG, unsigned int* __restrict__ g1pG) {
  int i = blockIdx.x * blockDim.x + threadIdx.x;
  if (i >= 50 * EMB) return;
  int kp = i / EMB, e = i % EMB;
  w1pG[i] = packbf2(w1[EMB * EMB + (2 * kp) * EMB + e], w1[EMB * EMB + (2 * kp + 1) * EMB + e]);
  g1pG[i] = packbf2(glu1w[e * EMB + 2 * kp], glu1w[e * EMB + 2 * kp + 1]);
}

// ---- Tier A+ SpMM pass 1 (in-place GS on bf16 table): ebf[w] <- bf16(emb_w + S*ebf) ----
__global__ void spmmP1_kernel(const int* __restrict__ rp, const unsigned int* __restrict__ cv,
                              const float2* __restrict__ emb2, unsigned int* __restrict__ ebf) {
  int w = (blockIdx.x * blockDim.x + threadIdx.x) >> 6;
  int lane = threadIdx.x & 63;
  if (w >= N_NODE || lane >= 50) return;
  int s = __builtin_amdgcn_readfirstlane(rp[w]);
  int e = __builtin_amdgcn_readfirstlane(rp[w + 1]);
  float ax[16], ay[16];
  #pragma unroll
  for (int k = 0; k < 16; ++k) { ax[k] = 0.f; ay[k] = 0.f; }
  for (int j = s; j < e; j += 16) {
    int   cc[16];
    float vv[16];
    #pragma unroll
    for (int k = 0; k < 16; ++k) {
      int jj = j + k;
      int jc = jj < e ? jj : e - 1;
      unsigned int u = cv[jc];
      cc[k] = (int)(u >> 15);
      float v = (float)(u & 0x7fffu) * (1.f / 327670.f);
      vv[k] = (jj < e) ? v : 0.f;
    }
    unsigned int uu[16];
    #pragma unroll
    for (int k = 0; k < 16; ++k) uu[k] = ebf[cc[k] * 50 + lane];
    #pragma unroll
    for (int k = 0; k < 16; ++k) { ax[k] += vv[k] * lo2f(uu[k]); ay[k] += vv[k] * hi2f(uu[k]); }
  }
  #pragma unroll
  for (int k = 0; k < 8; ++k) { ax[k] += ax[k + 8]; ay[k] += ay[k + 8]; }
  #pragma unroll
  for (int k = 0; k < 4; ++k) { ax[k] += ax[k + 4]; ay[k] += ay[k + 4]; }
  float sx = (ax[0] + ax[1]) + (ax[2] + ax[3]);
  float sy = (ay[0] + ay[1]) + (ay[2] + ay[3]);
  float2 ev = emb2[w * 50 + lane];
  ebf[w * 50 + lane] = packbf2(ev.x + sx, ev.y + sy);
}

// ---- Tier A+ SpMM pass 2: out[w](f32) = emb_w + S*ebf ----
__global__ void spmmP2_kernel(const int* __restrict__ rp, const unsigned int* __restrict__ cv,
                              const unsigned int* __restrict__ ebf,
                              const float2* __restrict__ emb2, float2* __restrict__ dst) {
  int w = (blockIdx.x * blockDim.x + threadIdx.x) >> 6;
  int lane = threadIdx.x & 63;
  if (w >= N_NODE || lane >= 50) return;
  int s = __builtin_amdgcn_readfirstlane(rp[w]);
  int e = __builtin_amdgcn_readfirstlane(rp[w + 1]);
  float ax[16], ay[16];
  #pragma unroll
  for (int k = 0; k < 16; ++k) { ax[k] = 0.f; ay[k] = 0.f; }
  for (int j = s; j < e; j += 16) {
    int   cc[16];
    float vv[16];
    #pragma unroll
    for (int k = 0; k < 16; ++k) {
      int jj = j + k;
      int jc = jj < e ? jj : e - 1;
      unsigned int u = cv[jc];
      cc[k] = (int)(u >> 15);
      float v = (float)(u & 0x7fffu) * (1.f / 327670.f);
      vv[k] = (jj < e) ? v : 0.f;
    }
    unsigned int uu[16];
    #pragma unroll
    for (int k = 0; k < 16; ++k) uu[k] = ebf[cc[k] * 50 + lane];
    #pragma unroll
    for (int k = 0; k < 16; ++k) { ax[k] += vv[k] * lo2f(uu[k]); ay[k] += vv[k] * hi2f(uu[k]); }
  }
  #pragma unroll
  for (int k = 0; k < 8; ++k) { ax[k] += ax[k + 8]; ay[k] += ay[k + 8]; }
  #pragma unroll
  for (int k = 0; k < 4; ++k) { ax[k] += ax[k + 4]; ay[k] += ay[k + 4]; }
  float sx = (ax[0] + ax[1]) + (ax[2] + ax[3]);
  float sy = (ay[0] + ay[1]) + (ay[2] + ay[3]);
  float2 ev = emb2[w * 50 + lane];
  dst[w * 50 + lane] = make_float2(ev.x + sx, ev.y + sy);
}

// ---------------- Tier A (fallback, f32 gathers): dst[w] = base[w] + S*gsrc ----------------
__global__ void spmmA_kernel(const int* __restrict__ rp, const unsigned int* __restrict__ cv,
                             const float2* __restrict__ gsrc, const float2* __restrict__ base,
                             float2* __restrict__ dst) {
  int w = (blockIdx.x * blockDim.x + threadIdx.x) >> 6;
  int lane = threadIdx.x & 63;
  if (w >= N_NODE || lane >= 50) return;
  int s = __builtin_amdgcn_readfirstlane(rp[w]);
  int e = __builtin_amdgcn_readfirstlane(rp[w + 1]);
  float ax[16], ay[16];
  #pragma unroll
  for (int k = 0; k < 16; ++k) { ax[k] = 0.f; ay[k] = 0.f; }
  for (int j = s; j < e; j += 16) {
    int   cc[16];
    float vv[16];
    #pragma unroll
    for (int k = 0; k < 16; ++k) {
      int jj = j + k;
      int jc = jj < e ? jj : e - 1;
      unsigned int u = cv[jc];
      cc[k] = (int)(u >> 15);
      float v = (float)(u & 0x7fffu) * (1.f / 327670.f);
      vv[k] = (jj < e) ? v : 0.f;
    }
    float2 uu[16];
    #pragma unroll
    for (int k = 0; k < 16; ++k) uu[k] = gsrc[cc[k] * 50 + lane];
    #pragma unroll
    for (int k = 0; k < 16; ++k) { ax[k] += vv[k] * uu[k].x; ay[k] += vv[k] * uu[k].y; }
  }
  #pragma unroll
  for (int k = 0; k < 8; ++k) { ax[k] += ax[k + 8]; ay[k] += ay[k + 8]; }
  #pragma unroll
  for (int k = 0; k < 4; ++k) { ax[k] += ax[k + 4]; ay[k] += ay[k + 4]; }
  float sx = (ax[0] + ax[1]) + (ax[2] + ax[3]);
  float sy = (ay[0] + ay[1]) + (ay[2] + ay[3]);
  float2 ev = base[w * 50 + lane];
  dst[w * 50 + lane] = make_float2(ev.x + sx, ev.y + sy);
}

__global__ void spmmB_kernel(const int* __restrict__ rp, const unsigned short* __restrict__ colHi,
                             const unsigned char* __restrict__ colLo,
                             const float2* __restrict__ gsrc, const float2* __restrict__ base,
                             float2* __restrict__ dst) {
  int w = (blockIdx.x * blockDim.x + threadIdx.x) >> 6;
  int lane = threadIdx.x & 63;
  if (w >= N_NODE || lane >= 50) return;
  int s = __builtin_amdgcn_readfirstlane(rp[w]);
  int e = __builtin_amdgcn_readfirstlane(rp[w + 1]);
  float ax[16], ay[16];
  #pragma unroll
  for (int k = 0; k < 16; ++k) { ax[k] = 0.f; ay[k] = 0.f; }
  for (int j = s; j < e; j += 16) {
    int   cc[16];
    float vv[16];
    #pragma unroll
    for (int k = 0; k < 16; ++k) {
      int jj = j + k;
      int jc = jj < e ? jj : e - 1;
      int hi = colHi[jc], lo = colLo[jc];
      cc[k] = (hi << 1) | (lo >> 7);
      float v = (float)(lo & 0x7f) * (1.f / 1270.f);
      vv[k] = (jj < e) ? v : 0.f;
    }
    float2 uu[16];
    #pragma unroll
    for (int k = 0; k < 16; ++k) uu[k] = gsrc[cc[k] * 50 + lane];
    #pragma unroll
    for (int k = 0; k < 16; ++k) { ax[k] += vv[k] * uu[k].x; ay[k] += vv[k] * uu[k].y; }
  }
  #pragma unroll
  for (int k = 0; k < 8; ++k) { ax[k] += ax[k + 8]; ay[k] += ay[k + 8]; }
  #pragma unroll
  for (int k = 0; k < 4; ++k) { ax[k] += ax[k + 4]; ay[k] += ay[k + 4]; }
  float sx = (ax[0] + ax[1]) + (ax[2] + ax[3]);
  float sy = (ay[0] + ay[1]) + (ay[2] + ay[3]);
  float2 ev = base[w * 50 + lane];
  dst[w * 50 + lane] = make_float2(ev.x + sx, ev.y + sy);
}

// ---------------- posW[l][e] = sum_k pos_w[l][k] * w1_top[k][e] ----------------
__global__ void posw_kernel(const float* __restrict__ pos_w, const float* __restrict__ w1,
                            float* __restrict__ posW) {
  __shared__ float sp[EMB];
  int l = blockIdx.x, e = threadIdx.x;
  if (e < EMB) sp[e] = pos_w[l * EMB + e];
  __syncthreads();
  if (e < EMB) {
    float a = 0.f;
    for (int k = 0; k < EMB; ++k) a += sp[k] * w1[k * EMB + e];
    posW[l * EMB + e] = a;
  }
}

// ---------------- fused session path v3: TWO 512-thread blocks per batch row --------------
// Grid 1024 = (b, h); block h handles l === h (mod 2) in the attention loop (25 l's).
// Proven R5 group structure kept: 4 groups x 128, group g gathers l === g (mod 4) and
// handles stored-row index m === g (mod 4) in the main loop. LDS cut to ~38 KB
// (seq stores only own-parity 25 rows; glu1^T weights read from a packed GLOBAL u32
// table, L1-resident) -> 3 blocks/CU co-resident (vs 2). acc partials combined by
// atomicAdd into memset-zeroed out_sess. Numerics identical to R5 modulo f32
// reassociation across halves.
__global__ __launch_bounds__(512, 6) void sess_kernel(
    const int* __restrict__ rsi, const int* __restrict__ si,
    const float* __restrict__ item_hg,   // f32 (d_out item region, finalized)
    const float* __restrict__ emb, const float* __restrict__ slen,
    const float* __restrict__ posW,
    const unsigned int* __restrict__ w1pG, const unsigned int* __restrict__ g1pG,
    const float* __restrict__ glu1b,
    const float* __restrict__ glu2w, const float* __restrict__ w2,
    const float* __restrict__ maskp,
    float* __restrict__ X, float* __restrict__ Z,
    float* __restrict__ out_sess) {
  __shared__ __align__(16) float seqL[25 * EMB];       // 10 KB (own-parity rows, idx l>>1)
  __shared__ unsigned int w1p[50 * EMB];               // 20 KB packed bf16 pairs of w_1 bottom
  __shared__ float hsL[EMB];
  __shared__ __align__(16) float nhL[4][EMB];
  __shared__ float hsP[4][EMB];
  __shared__ float s0P[4][EMB];
  __shared__ float hsgP[4][EMB];
  __shared__ float accP[4][EMB];
  __shared__ float redg[4][2];
  int bh = blockIdx.x;
  int b = bh >> 1, h = bh & 1;
  int t = threadIdx.x;
  int g = t >> 7;          // group 0..3 (parity of g == parity of its gathered l's)
  int e = t & 127;         // 0..127 within group
  bool act = e < EMB;

  // stage w1p from packed global table (plain u32 copy)
  for (int i = t; i < 50 * EMB; i += 512) w1p[i] = w1pG[i];

  float inv = 1.f / slen[b];

  // gather: group g covers l === g (mod 4) (for full hs/s0 sums);
  // stores seq row only when its parity matches this block's half.
  float hsacc = 0.f, s0acc = 0.f;
  bool store = ((g & 1) == h);
  if (act) {
    for (int l = g; l < SEQ; l += 4) {
      int i1 = rsi[b * SEQ + l];
      float sv_ = (i1 > 0) ? item_hg[(i1 - 1) * EMB + e] : 0.f;
      if (store) seqL[(l >> 1) * EMB + e] = sv_;
      hsacc += sv_;
      int i0 = si[b * SEQ + l];
      if (i0 > 0) s0acc += emb[(i0 - 1) * EMB + e];
    }
    hsP[g][e] = hsacc;
    s0P[g][e] = s0acc;
  }
  __syncthreads();
  if (act && g == 0) {
    float hv = (hsP[0][e] + hsP[1][e] + hsP[2][e] + hsP[3][e]) * inv;
    hsL[e] = hv;
    if (h == 0) {
      float sv = (s0P[0][e] + s0P[1][e] + s0P[2][e] + s0P[3][e]) * inv;
      X[b * EMB + e] = sv;
      Z[b * EMB + e] = sv;
    }
  }
  __syncthreads();

  // hsgv[e] = glu1b[e] + sum_k hsL[k]*glu2w[e*EMB+k], k split across groups
  if (act) {
    float a = 0.f;
    int k0 = g * 25;
    for (int k = k0; k < k0 + 25; ++k) a += hsL[k] * glu2w[e * EMB + k];
    hsgP[g][e] = a;
  }
  __syncthreads();
  float hsgv = 0.f, w2v = 0.f;
  if (act) {
    hsgv = glu1b[e] + hsgP[0][e] + hsgP[1][e] + hsgP[2][e] + hsgP[3][e];
    w2v = w2[e];
  }

  float acc = 0.f;
  for (int it = 0; it < 7; ++it) {
    int m = it * 4 + g;          // stored-row index 0..24
    bool lv = m < 25;
    int l = h + 2 * m;           // original sequence position
    asm volatile("" ::: "memory");   // block LICM of loop-invariant global weight loads
    __syncthreads();
    if (act && lv) {
      const float4* sq4 = (const float4*)&seqL[m * EMB];
      float a0 = 0.f, a1 = 0.f, a2 = 0.f, a3 = 0.f;
      #pragma unroll
      for (int i = 0; i < 25; ++i) {
        float4 sv = sq4[i];
        unsigned int p0 = w1p[(2 * i) * EMB + e];
        unsigned int p1 = w1p[(2 * i + 1) * EMB + e];
        a0 += sv.x * lo2f(p0);
        a1 += sv.y * hi2f(p0);
        a2 += sv.z * lo2f(p1);
        a3 += sv.w * hi2f(p1);
      }
      float nh = posW[l * EMB + e] + ((a0 + a1) + (a2 + a3));
      nhL[g][e] = tanhf(nh);
    }
    __syncthreads();
    float p = 0.f;
    if (act && lv) {
      const float4* nq4 = (const float4*)nhL[g];
      float a0 = hsgv, a1 = 0.f, a2 = 0.f, a3 = 0.f;
      #pragma unroll
      for (int i = 0; i < 25; ++i) {
        float4 nv = nq4[i];
        unsigned int p0 = g1pG[(2 * i) * EMB + e];   // coalesced, L1-resident 20 KB table
        unsigned int p1 = g1pG[(2 * i + 1) * EMB + e];
        a0 += nv.x * lo2f(p0);
        a1 += nv.y * hi2f(p0);
        a2 += nv.z * lo2f(p1);
        a3 += nv.w * hi2f(p1);
      }
      float a = (a0 + a1) + (a2 + a3);
      float gs = 1.f / (1.f + __expf(-a));
      p = gs * w2v;
    }
    for (int off = 32; off; off >>= 1) p += __shfl_down(p, off, 64);
    if ((t & 63) == 0) redg[g][(t >> 6) & 1] = p;
    __syncthreads();
    if (act && lv) {
      float att = (redg[g][0] + redg[g][1]) * maskp[b * SEQ + l];
      acc += att * seqL[m * EMB + e];
    }
  }
  if (act) accP[g][e] = acc;
  __syncthreads();
  if (act && g == 0) {
    float s = accP[0][e] + accP[1][e] + accP[2][e] + accP[3][e];
    atomicAdd(&out_sess[b * EMB + e], s);
  }
}

// ---------------- LineConv mat-vec: y = M @ x (all f32), optional Z += y ----------------
__global__ void mv_kernel(const float* __restrict__ M, const float* __restrict__ x,
                          float* __restrict__ y, float* __restrict__ Zacc) {
  __shared__ float Ms[BATCH];
  int b = blockIdx.x, t = threadIdx.x;
  for (int i = t; i < BATCH; i += 128) Ms[i] = M[b * BATCH + i];
  __syncthreads();
  if (t < EMB) {
    float a = 0.f;
    for (int k = 0; k < BATCH; ++k) a += Ms[k] * x[k * EMB + t];
    y[b * EMB + t] = a;
    if (Zacc) Zacc[b * EMB + t] += a;
  }
}

// ---------------- SSL loss: scaled atomicAdd straight into out_loss ----------------
__global__ void ssl_kernel(const float* __restrict__ Z, const float* __restrict__ hg,
                           const int* __restrict__ pr, const int* __restrict__ pc,
                           float* __restrict__ loss_out) {
  __shared__ float r1[128], r2[128];
  int b = blockIdx.x, t = threadIdx.x;
  float p1 = 0.f, p2 = 0.f;
  if (t < EMB) {
    float lg = Z[b * EMB + t];
    p1 = lg * hg[b * EMB + t];
    p2 = lg * hg[pr[b] * EMB + pc[t]];
  }
  r1[t] = p1; r2[t] = p2;
  __syncthreads();
  for (int off = 64; off; off >>= 1) {
    if (t < off) { r1[t] += r1[t + off]; r2[t] += r2[t + off]; }
    __syncthreads();
  }
  if (t == 0) {
    float sp = 1.f / (1.f + expf(-r1[0]));
    float sn = 1.f / (1.f + expf(-r2[0]));
    atomicAdd(loss_out, 0.01f * (-logf(1e-8f + sp) - logf(1e-8f + (1.f - sn))));
  }
}

extern "C" void kernel_launch(void* const* d_in, const int* in_sizes, int n_in,
                              void* d_out, int out_size, void* d_ws, size_t ws_size,
                              hipStream_t stream) {
  const int*   session_item = (const int*)d_in[0];
  const float* slen   = (const float*)d_in[1];
  const float* D      = (const float*)d_in[2];
  const float* A      = (const float*)d_in[3];
  const int*   rsi    = (const int*)d_in[4];
  const float* mask   = (const float*)d_in[5];
  const float* emb    = (const float*)d_in[6];
  const float* posw   = (const float*)d_in[7];
  const float* w1     = (const float*)d_in[8];
  const float* w2     = (const float*)d_in[9];
  const float* glu1w  = (const float*)d_in[10];
  const float* glu1b  = (const float*)d_in[11];
  const float* glu2w  = (const float*)d_in[12];
  const int*   adj_rows = (const int*)d_in[13];
  const int*   adj_cols = (const int*)d_in[14];
  const float* adj_vals = (const float*)d_in[15];
  const int*   pr     = (const int*)d_in[16];
  const int*   pc     = (const int*)d_in[17];

  // f32 OUTPUT layout: item [0,1e7), sess [1e7,1e7+51200), loss [+51200]
  float* out_item = (float*)d_out;
  float* out_sess = out_item + (size_t)N_NODE * EMB;
  float* out_loss = out_sess + (size_t)BATCH * EMB;
  float2* out2    = (float2*)d_out;
  const float2* emb2 = (const float2*)emb;

  char* ws = (char*)d_ws;
  size_t off = 0;
  auto alloc = [&](size_t bytes) -> void* {
    void* p = ws + off;
    off = (off + bytes + 255) & ~(size_t)255;
    return p;
  };

  hipMemsetAsync(out_loss, 0, 4, stream);
  hipMemsetAsync(out_sess, 0, (size_t)BATCH * EMB * 4, stream);  // sess v3 accumulates

  if (ws_size >= 25500000) {
    // ===== TIER A+ (~25.5 MB): packed u32 CSR + bf16 in-place gather table =====
    int*          counts  = (int*)alloc((size_t)N_NODE * 4);
    int*          row_ptr = (int*)alloc((size_t)(N_NODE + 1) * 4);
    int*          partial = (int*)alloc((size_t)SCAN_NB * 4);
    unsigned int* cv      = (unsigned int*)alloc((size_t)NNZ * 4);
    unsigned int* ebf     = (unsigned int*)alloc((size_t)N_NODE * 50 * 4);  // 20 MB
    float* posW = (float*)alloc((size_t)SEQ * EMB * 4);
    float* X    = (float*)alloc((size_t)BATCH * EMB * 4);
    float* Y    = (float*)alloc((size_t)BATCH * EMB * 4);
    float* Z    = (float*)alloc((size_t)BATCH * EMB * 4);
    unsigned int* w1pG = (unsigned int*)alloc((size_t)50 * EMB * 4);
    unsigned int* g1pG = (unsigned int*)alloc((size_t)50 * EMB * 4);

    hipMemsetAsync(counts, 0, (size_t)N_NODE * 4, stream);

    hist_kernel<<<(NNZ + 255) / 256, 256, 0, stream>>>(adj_rows, counts);
    scan_partial_kernel<<<SCAN_NB, 256, 0, stream>>>(counts, partial);
    scan_top_kernel<<<1, 128, 0, stream>>>(partial, row_ptr);
    scan_final_kernel<<<SCAN_NB, 256, 0, stream>>>(partial, counts, row_ptr);
    scatterA_kernel<<<(NNZ + 255) / 256, 256, 0, stream>>>(adj_rows, adj_cols, adj_vals,
                                                           counts, cv);
    packbf_kernel<<<(N_NODE * 50 + 255) / 256, 256, 0, stream>>>(emb2, ebf);
    spmmP1_kernel<<<N_NODE / 4, 256, 0, stream>>>(row_ptr, cv, emb2, ebf);
    spmmP2_kernel<<<N_NODE / 4, 256, 0, stream>>>(row_ptr, cv, ebf, emb2, out2);

    packw_kernel<<<(50 * EMB + 255) / 256, 256, 0, stream>>>(w1, glu1w, w1pG, g1pG);
    posw_kernel<<<SEQ, 128, 0, stream>>>(posw, w1, posW);
    sess_kernel<<<BATCH * 2, 512, 0, stream>>>(rsi, session_item, out_item, emb, slen, posW,
                                               w1pG, g1pG, glu1b, glu2w, w2, mask,
                                               X, Z, out_sess);
    mv_kernel<<<BATCH, 128, 0, stream>>>(A, X, Y, (float*)nullptr);
    mv_kernel<<<BATCH, 128, 0, stream>>>(D, Y, X, Z);
    mv_kernel<<<BATCH, 128, 0, stream>>>(A, X, Y, (float*)nullptr);
    mv_kernel<<<BATCH, 128, 0, stream>>>(D, Y, X, Z);
    ssl_kernel<<<BATCH, 128, 0, stream>>>(Z, out_sess, pr, pc, out_loss);
  } else if (ws_size >= 5600000) {
    // ===== TIER A (~5.5 MB): packed u32 CSR, f32 gathers =====
    int*          counts  = (int*)alloc((size_t)N_NODE * 4);
    int*          row_ptr = (int*)alloc((size_t)(N_NODE + 1) * 4);
    int*          partial = (int*)alloc((size_t)SCAN_NB * 4);
    unsigned int* cv      = (unsigned int*)alloc((size_t)NNZ * 4);
    float* posW = (float*)alloc((size_t)SEQ * EMB * 4);
    float* X    = (float*)alloc((size_t)BATCH * EMB * 4);
    float* Y    = (float*)alloc((size_t)BATCH * EMB * 4);
    float* Z    = (float*)alloc((size_t)BATCH * EMB * 4);
    unsigned int* w1pG = (unsigned int*)alloc((size_t)50 * EMB * 4);
    unsigned int* g1pG = (unsigned int*)alloc((size_t)50 * EMB * 4);

    hipMemsetAsync(counts, 0, (size_t)N_NODE * 4, stream);

    hist_kernel<<<(NNZ + 255) / 256, 256, 0, stream>>>(adj_rows, counts);
    scan_partial_kernel<<<SCAN_NB, 256, 0, stream>>>(counts, partial);
    scan_top_kernel<<<1, 128, 0, stream>>>(partial, row_ptr);
    scan_final_kernel<<<SCAN_NB, 256, 0, stream>>>(partial, counts, row_ptr);
    scatterA_kernel<<<(NNZ + 255) / 256, 256, 0, stream>>>(adj_rows, adj_cols, adj_vals,
                                                           counts, cv);
    spmmA_kernel<<<N_NODE / 4, 256, 0, stream>>>(row_ptr, cv, emb2, emb2, out2);
    spmmA_kernel<<<N_NODE / 4, 256, 0, stream>>>(row_ptr, cv, out2, emb2, out2);

    packw_kernel<<<(50 * EMB + 255) / 256, 256, 0, stream>>>(w1, glu1w, w1pG, g1pG);
    posw_kernel<<<SEQ, 128, 0, stream>>>(posw, w1, posW);
    sess_kernel<<<BATCH * 2, 512, 0, stream>>>(rsi, session_item, out_item, emb, slen, posW,
                                               w1pG, g1pG, glu1b, glu2w, w2, mask,
                                               X, Z, out_sess);
    mv_kernel<<<BATCH, 128, 0, stream>>>(A, X, Y, (float*)nullptr);
    mv_kernel<<<BATCH, 128, 0, stream>>>(D, Y, X, Z);
    mv_kernel<<<BATCH, 128, 0, stream>>>(A, X, Y, (float*)nullptr);
    mv_kernel<<<BATCH, 128, 0, stream>>>(D, Y, X, Z);
    ssl_kernel<<<BATCH, 128, 0, stream>>>(Z, out_sess, pr, pc, out_loss);
  } else {
    // ===== TIER B (~4.1 MB): 3-byte CSR; counts unioned with session scratch =====
    unsigned short* colHi  = (unsigned short*)alloc((size_t)NNZ * 2);   // 2.0 MB
    unsigned char*  colLo  = (unsigned char*)alloc((size_t)NNZ);        // 1.0 MB
    int*            row_ptr = (int*)alloc((size_t)(N_NODE + 1) * 4);    // 0.4 MB
    int*            partial = (int*)alloc((size_t)SCAN_NB * 4);         // 0.4 KB
    size_t u0 = off;
    int*   counts = (int*)alloc((size_t)N_NODE * 4);                    // 0.4 MB
    off = u0;  // union: session scratch overlays counts (dead after scatter)
    float* posW = (float*)alloc((size_t)SEQ * EMB * 4);
    float* X    = (float*)alloc((size_t)BATCH * EMB * 4);
    float* Y    = (float*)alloc((size_t)BATCH * EMB * 4);
    float* Z    = (float*)alloc((size_t)BATCH * EMB * 4);
    unsigned int* w1pG = (unsigned int*)alloc((size_t)50 * EMB * 4);
    unsigned int* g1pG = (unsigned int*)alloc((size_t)50 * EMB * 4);

    hipMemsetAsync(counts, 0, (size_t)N_NODE * 4, stream);

    hist_kernel<<<(NNZ + 255) / 256, 256, 0, stream>>>(adj_rows, counts);
    scan_partial_kernel<<<SCAN_NB, 256, 0, stream>>>(counts, partial);
    scan_top_kernel<<<1, 128, 0, stream>>>(partial, row_ptr);
    scan_final_kernel<<<SCAN_NB, 256, 0, stream>>>(partial, counts, row_ptr);
    scatterB_kernel<<<(NNZ + 255) / 256, 256, 0, stream>>>(adj_rows, adj_cols, adj_vals,
                                                           counts, colHi, colLo);
    spmmB_kernel<<<N_NODE / 4, 256, 0, stream>>>(row_ptr, colHi, colLo, emb2, emb2, out2);
    spmmB_kernel<<<N_NODE / 4, 256, 0, stream>>>(row_ptr, colHi, colLo, out2, emb2, out2);

    packw_kernel<<<(50 * EMB + 255) / 256, 256, 0, stream>>>(w1, glu1w, w1pG, g1pG);
    posw_kernel<<<SEQ, 128, 0, stream>>>(posw, w1, posW);
    sess_kernel<<<BATCH * 2, 512, 0, stream>>>(rsi, session_item, out_item, emb, slen, posW,
                                               w1pG, g1pG, glu1b, glu2w, w2, mask,
                                               X, Z, out_sess);
    mv_kernel<<<BATCH, 128, 0, stream>>>(A, X, Y, (float*)nullptr);
    mv_kernel<<<BATCH, 128, 0, stream>>>(D, Y, X, Z);
    mv_kernel<<<BATCH, 128, 0, stream>>>(A, X, Y, (float*)nullptr);
    mv_kernel<<<BATCH, 128, 0, stream>>>(D, Y, X, Z);
    ssl_kernel<<<BATCH, 128, 0, stream>>>(Z, out_sess, pr, pc, out_loss);
  }
}

// Round 12
// 523.329 us; speedup vs baseline: 1.5635x; 1.5635x over previous
//
#include <hip/hip_runtime.h>
#include <math.h>

#define N_NODE 100000
#define EMB    100
#define BATCH  512
#define SEQ    50
#define NNZ    1000000

#define SCAN_CHUNK 1024
#define SCAN_NB ((N_NODE + SCAN_CHUNK - 1) / SCAN_CHUNK)   // 98
#define HIST_NB ((NNZ + 255) / 256)                        // 3907
#define PACK_NB ((N_NODE * 50 + 255) / 256)                // 19532

static __device__ __forceinline__ float bf2f(unsigned short u) {
  union { unsigned int i; float f; } v; v.i = ((unsigned int)u) << 16; return v.f;
}
static __device__ __forceinline__ unsigned short f2bf(float f) {
  union { float f; unsigned int i; } v; v.f = f;
  unsigned int i = v.i;
  return (unsigned short)((i + 0x7fffu + ((i >> 16) & 1u)) >> 16);  // RNE
}
static __device__ __forceinline__ float lo2f(unsigned int u) {
  union { unsigned int i; float f; } v; v.i = u << 16; return v.f;
}
static __device__ __forceinline__ float hi2f(unsigned int u) {
  union { unsigned int i; float f; } v; v.i = u & 0xffff0000u; return v.f;
}
static __device__ __forceinline__ unsigned int packbf2(float x, float y) {
  return (unsigned int)f2bf(x) | ((unsigned int)f2bf(y) << 16);
}

// ---------------- CSR build ----------------
__global__ void hist_kernel(const int* __restrict__ rows, int* __restrict__ counts) {
  int i = blockIdx.x * blockDim.x + threadIdx.x;
  if (i < NNZ) atomicAdd(&counts[rows[i]], 1);
}

// Fused: hist (atomic-latency-bound) overlapped with bf16 table pack (streaming).
// Independent inputs/outputs; block-range split.
__global__ void hist_packbf_kernel(const int* __restrict__ rows, int* __restrict__ counts,
                                   const float2* __restrict__ src, unsigned int* __restrict__ dst) {
  int blk = blockIdx.x;
  if (blk < HIST_NB) {
    int i = blk * 256 + threadIdx.x;
    if (i < NNZ) atomicAdd(&counts[rows[i]], 1);
  } else {
    int i = (blk - HIST_NB) * 256 + threadIdx.x;
    if (i < N_NODE * 50) {
      float2 v = src[i];
      dst[i] = packbf2(v.x, v.y);
    }
  }
}

// ---- multi-block two-level exclusive scan ----
__global__ void scan_partial_kernel(const int* __restrict__ counts, int* __restrict__ partial) {
  __shared__ int red[256];
  int b = blockIdx.x, t = threadIdx.x;
  int base = b * SCAN_CHUNK;
  int s = 0;
  #pragma unroll
  for (int k = 0; k < SCAN_CHUNK; k += 256) {
    int idx = base + k + t;
    if (idx < N_NODE) s += counts[idx];
  }
  red[t] = s;
  __syncthreads();
  for (int off = 128; off; off >>= 1) {
    if (t < off) red[t] += red[t + off];
    __syncthreads();
  }
  if (t == 0) partial[b] = red[0];
}

__global__ void scan_top_kernel(int* __restrict__ partial, int* __restrict__ row_ptr) {
  __shared__ int s[128];
  int t = threadIdx.x;                    // 128 threads, 1 block
  int v = (t < SCAN_NB) ? partial[t] : 0;
  s[t] = v;
  __syncthreads();
  for (int off = 1; off < 128; off <<= 1) {
    int u = (t >= off) ? s[t - off] : 0;
    __syncthreads();
    s[t] += u;
    __syncthreads();
  }
  if (t < SCAN_NB) partial[t] = (t == 0) ? 0 : s[t - 1];   // exclusive block offsets
  if (t == 127) row_ptr[N_NODE] = s[127];                  // total nnz
}

__global__ void scan_final_kernel(const int* __restrict__ partial,
                                  int* __restrict__ counts_cursor,
                                  int* __restrict__ row_ptr) {
  __shared__ int s[256];
  int b = blockIdx.x, t = threadIdx.x;
  int base = b * SCAN_CHUNK + t * 4;
  int c[4];
  #pragma unroll
  for (int k = 0; k < 4; ++k) {
    int idx = base + k;
    c[k] = (idx < N_NODE) ? counts_cursor[idx] : 0;
  }
  int local = c[0] + c[1] + c[2] + c[3];
  s[t] = local;
  __syncthreads();
  for (int off = 1; off < 256; off <<= 1) {
    int u = (t >= off) ? s[t - off] : 0;
    __syncthreads();
    s[t] += u;
    __syncthreads();
  }
  int prefix = partial[b] + ((t == 0) ? 0 : s[t - 1]);
  #pragma unroll
  for (int k = 0; k < 4; ++k) {
    int idx = base + k;
    if (idx < N_NODE) {
      row_ptr[idx] = prefix;
      counts_cursor[idx] = prefix;
      prefix += c[k];
    }
  }
}

// Tier A: packed CSR, one u32 per nnz: (col<<15) | q15, q15 = round(v*327670)
__global__ void scatterA_kernel(const int* __restrict__ rows, const int* __restrict__ cols,
                                const float* __restrict__ vals, int* __restrict__ cursor,
                                unsigned int* __restrict__ cv) {
  int i = blockIdx.x * blockDim.x + threadIdx.x;
  if (i >= NNZ) return;
  int p = atomicAdd(&cursor[rows[i]], 1);
  int q = (int)rintf(vals[i] * 327670.f);
  q = q < 0 ? 0 : (q > 32767 ? 32767 : q);
  cv[p] = ((unsigned int)cols[i] << 15) | (unsigned int)q;
}

// Tier B: colHi=col>>1 (u16); colLo=(col&1)<<7 | q7, q7=round(v*1270) (err <= 4e-4)
__global__ void scatterB_kernel(const int* __restrict__ rows, const int* __restrict__ cols,
                                const float* __restrict__ vals, int* __restrict__ cursor,
                                unsigned short* __restrict__ colHi, unsigned char* __restrict__ colLo) {
  int i = blockIdx.x * blockDim.x + threadIdx.x;
  if (i >= NNZ) return;
  int p = atomicAdd(&cursor[rows[i]], 1);
  int c = cols[i];
  int q = (int)rintf(vals[i] * 1270.f);
  q = q < 0 ? 0 : (q > 127 ? 127 : q);
  colHi[p] = (unsigned short)(c >> 1);
  colLo[p] = (unsigned char)(((c & 1) << 7) | q);
}

// ---- Tier A+ SpMM pass 1 (in-place GS on bf16 table): ebf[w] <- bf16(emb_w + S*ebf) ----
__global__ void spmmP1_kernel(const int* __restrict__ rp, const unsigned int* __restrict__ cv,
                              const float2* __restrict__ emb2, unsigned int* __restrict__ ebf) {
  int w = (blockIdx.x * blockDim.x + threadIdx.x) >> 6;
  int lane = threadIdx.x & 63;
  if (w >= N_NODE || lane >= 50) return;
  int s = __builtin_amdgcn_readfirstlane(rp[w]);
  int e = __builtin_amdgcn_readfirstlane(rp[w + 1]);
  float ax[16], ay[16];
  #pragma unroll
  for (int k = 0; k < 16; ++k) { ax[k] = 0.f; ay[k] = 0.f; }
  for (int j = s; j < e; j += 16) {
    int   cc[16];
    float vv[16];
    #pragma unroll
    for (int k = 0; k < 16; ++k) {
      int jj = j + k;
      int jc = jj < e ? jj : e - 1;
      unsigned int u = cv[jc];
      cc[k] = (int)(u >> 15);
      float v = (float)(u & 0x7fffu) * (1.f / 327670.f);
      vv[k] = (jj < e) ? v : 0.f;
    }
    unsigned int uu[16];
    #pragma unroll
    for (int k = 0; k < 16; ++k) uu[k] = ebf[cc[k] * 50 + lane];
    #pragma unroll
    for (int k = 0; k < 16; ++k) { ax[k] += vv[k] * lo2f(uu[k]); ay[k] += vv[k] * hi2f(uu[k]); }
  }
  #pragma unroll
  for (int k = 0; k < 8; ++k) { ax[k] += ax[k + 8]; ay[k] += ay[k + 8]; }
  #pragma unroll
  for (int k = 0; k < 4; ++k) { ax[k] += ax[k + 4]; ay[k] += ay[k + 4]; }
  float sx = (ax[0] + ax[1]) + (ax[2] + ax[3]);
  float sy = (ay[0] + ay[1]) + (ay[2] + ay[3]);
  float2 ev = emb2[w * 50 + lane];
  ebf[w * 50 + lane] = packbf2(ev.x + sx, ev.y + sy);
}

// ---- Tier A+ SpMM pass 2: out[w](f32) = emb_w + S*ebf ----
__global__ void spmmP2_kernel(const int* __restrict__ rp, const unsigned int* __restrict__ cv,
                              const unsigned int* __restrict__ ebf,
                              const float2* __restrict__ emb2, float2* __restrict__ dst) {
  int w = (blockIdx.x * blockDim.x + threadIdx.x) >> 6;
  int lane = threadIdx.x & 63;
  if (w >= N_NODE || lane >= 50) return;
  int s = __builtin_amdgcn_readfirstlane(rp[w]);
  int e = __builtin_amdgcn_readfirstlane(rp[w + 1]);
  float ax[16], ay[16];
  #pragma unroll
  for (int k = 0; k < 16; ++k) { ax[k] = 0.f; ay[k] = 0.f; }
  for (int j = s; j < e; j += 16) {
    int   cc[16];
    float vv[16];
    #pragma unroll
    for (int k = 0; k < 16; ++k) {
      int jj = j + k;
      int jc = jj < e ? jj : e - 1;
      unsigned int u = cv[jc];
      cc[k] = (int)(u >> 15);
      float v = (float)(u & 0x7fffu) * (1.f / 327670.f);
      vv[k] = (jj < e) ? v : 0.f;
    }
    unsigned int uu[16];
    #pragma unroll
    for (int k = 0; k < 16; ++k) uu[k] = ebf[cc[k] * 50 + lane];
    #pragma unroll
    for (int k = 0; k < 16; ++k) { ax[k] += vv[k] * lo2f(uu[k]); ay[k] += vv[k] * hi2f(uu[k]); }
  }
  #pragma unroll
  for (int k = 0; k < 8; ++k) { ax[k] += ax[k + 8]; ay[k] += ay[k + 8]; }
  #pragma unroll
  for (int k = 0; k < 4; ++k) { ax[k] += ax[k + 4]; ay[k] += ay[k + 4]; }
  float sx = (ax[0] + ax[1]) + (ax[2] + ax[3]);
  float sy = (ay[0] + ay[1]) + (ay[2] + ay[3]);
  float2 ev = emb2[w * 50 + lane];
  dst[w * 50 + lane] = make_float2(ev.x + sx, ev.y + sy);
}

// ---------------- Tier A (fallback, f32 gathers): dst[w] = base[w] + S*gsrc ----------------
__global__ void spmmA_kernel(const int* __restrict__ rp, const unsigned int* __restrict__ cv,
                             const float2* __restrict__ gsrc, const float2* __restrict__ base,
                             float2* __restrict__ dst) {
  int w = (blockIdx.x * blockDim.x + threadIdx.x) >> 6;
  int lane = threadIdx.x & 63;
  if (w >= N_NODE || lane >= 50) return;
  int s = __builtin_amdgcn_readfirstlane(rp[w]);
  int e = __builtin_amdgcn_readfirstlane(rp[w + 1]);
  float ax[16], ay[16];
  #pragma unroll
  for (int k = 0; k < 16; ++k) { ax[k] = 0.f; ay[k] = 0.f; }
  for (int j = s; j < e; j += 16) {
    int   cc[16];
    float vv[16];
    #pragma unroll
    for (int k = 0; k < 16; ++k) {
      int jj = j + k;
      int jc = jj < e ? jj : e - 1;
      unsigned int u = cv[jc];
      cc[k] = (int)(u >> 15);
      float v = (float)(u & 0x7fffu) * (1.f / 327670.f);
      vv[k] = (jj < e) ? v : 0.f;
    }
    float2 uu[16];
    #pragma unroll
    for (int k = 0; k < 16; ++k) uu[k] = gsrc[cc[k] * 50 + lane];
    #pragma unroll
    for (int k = 0; k < 16; ++k) { ax[k] += vv[k] * uu[k].x; ay[k] += vv[k] * uu[k].y; }
  }
  #pragma unroll
  for (int k = 0; k < 8; ++k) { ax[k] += ax[k + 8]; ay[k] += ay[k + 8]; }
  #pragma unroll
  for (int k = 0; k < 4; ++k) { ax[k] += ax[k + 4]; ay[k] += ay[k + 4]; }
  float sx = (ax[0] + ax[1]) + (ax[2] + ax[3]);
  float sy = (ay[0] + ay[1]) + (ay[2] + ay[3]);
  float2 ev = base[w * 50 + lane];
  dst[w * 50 + lane] = make_float2(ev.x + sx, ev.y + sy);
}

__global__ void spmmB_kernel(const int* __restrict__ rp, const unsigned short* __restrict__ colHi,
                             const unsigned char* __restrict__ colLo,
                             const float2* __restrict__ gsrc, const float2* __restrict__ base,
                             float2* __restrict__ dst) {
  int w = (blockIdx.x * blockDim.x + threadIdx.x) >> 6;
  int lane = threadIdx.x & 63;
  if (w >= N_NODE || lane >= 50) return;
  int s = __builtin_amdgcn_readfirstlane(rp[w]);
  int e = __builtin_amdgcn_readfirstlane(rp[w + 1]);
  float ax[16], ay[16];
  #pragma unroll
  for (int k = 0; k < 16; ++k) { ax[k] = 0.f; ay[k] = 0.f; }
  for (int j = s; j < e; j += 16) {
    int   cc[16];
    float vv[16];
    #pragma unroll
    for (int k = 0; k < 16; ++k) {
      int jj = j + k;
      int jc = jj < e ? jj : e - 1;
      int hi = colHi[jc], lo = colLo[jc];
      cc[k] = (hi << 1) | (lo >> 7);
      float v = (float)(lo & 0x7f) * (1.f / 1270.f);
      vv[k] = (jj < e) ? v : 0.f;
    }
    float2 uu[16];
    #pragma unroll
    for (int k = 0; k < 16; ++k) uu[k] = gsrc[cc[k] * 50 + lane];
    #pragma unroll
    for (int k = 0; k < 16; ++k) { ax[k] += vv[k] * uu[k].x; ay[k] += vv[k] * uu[k].y; }
  }
  #pragma unroll
  for (int k = 0; k < 8; ++k) { ax[k] += ax[k + 8]; ay[k] += ay[k + 8]; }
  #pragma unroll
  for (int k = 0; k < 4; ++k) { ax[k] += ax[k + 4]; ay[k] += ay[k + 4]; }
  float sx = (ax[0] + ax[1]) + (ax[2] + ax[3]);
  float sy = (ay[0] + ay[1]) + (ay[2] + ay[3]);
  float2 ev = base[w * 50 + lane];
  dst[w * 50 + lane] = make_float2(ev.x + sx, ev.y + sy);
}

// ---------------- posW[l][e] = sum_k pos_w[l][k] * w1_top[k][e] ----------------
__global__ void posw_kernel(const float* __restrict__ pos_w, const float* __restrict__ w1,
                            float* __restrict__ posW) {
  __shared__ float sp[EMB];
  int l = blockIdx.x, e = threadIdx.x;
  if (e < EMB) sp[e] = pos_w[l * EMB + e];
  __syncthreads();
  if (e < EMB) {
    float a = 0.f;
    for (int k = 0; k < EMB; ++k) a += sp[k] * w1[k * EMB + e];
    posW[l * EMB + e] = a;
  }
}

// ---------------- fused session path: one 512-thread block per batch row ----------------
// PROVEN structure (82 us, zero scratch; R8/R10): 4 groups of 128 threads, group g owns
// l === g (mod 4), ONE output column per thread. The sess inner loops REQUIRE:
// LDS weight reads + one-output-per-thread + >=128 VGPR budget -- every deviation
// (R6 barrier-free, R7 two-cols, R11 global-weights + launch_bounds(512,6)) spilled
// ~1 KB/thread to scratch (hundreds of MB of FETCH/WRITE). Do not restructure without
// checking WRITE_SIZE for scratch.
__global__ __launch_bounds__(512, 4) void sess_kernel(
    const int* __restrict__ rsi, const int* __restrict__ si,
    const float* __restrict__ item_hg,   // f32 (d_out item region, finalized)
    const float* __restrict__ emb, const float* __restrict__ slen,
    const float* __restrict__ posW, const float* __restrict__ w1,
    const float* __restrict__ glu1w, const float* __restrict__ glu1b,
    const float* __restrict__ glu2w, const float* __restrict__ w2,
    const float* __restrict__ maskp,
    float* __restrict__ X, float* __restrict__ Z,
    float* __restrict__ out_sess) {
  __shared__ __align__(16) float seq[SEQ * EMB];       // 20 KB (f32 item rows)
  __shared__ unsigned int w1p[50 * EMB];               // 20 KB packed bf16 pairs of w_1 bottom
  __shared__ unsigned int g1p[50 * EMB];               // 20 KB packed bf16 pairs of glu1_w^T
  __shared__ float hsL[EMB];
  __shared__ __align__(16) float nhL[4][EMB];
  __shared__ float hsP[4][EMB];
  __shared__ float s0P[4][EMB];
  __shared__ float hsgP[4][EMB];
  __shared__ float accP[4][EMB];
  __shared__ float redg[4][2];
  int b = blockIdx.x, t = threadIdx.x;
  int g = t >> 7;          // group 0..3
  int e = t & 127;         // 0..127 within group
  bool act = e < EMB;

  // cooperative staging: pack (k=2kp, k=2kp+1) bf16 into one u32 at [kp*EMB+e]
  for (int i = t; i < 50 * EMB; i += 512) {
    int kp = i / EMB, e2 = i % EMB;
    unsigned int b0 = f2bf(w1[EMB * EMB + (2 * kp) * EMB + e2]);
    unsigned int b1 = f2bf(w1[EMB * EMB + (2 * kp + 1) * EMB + e2]);
    w1p[i] = b0 | (b1 << 16);
    unsigned int c0 = f2bf(glu1w[e2 * EMB + 2 * kp]);
    unsigned int c1 = f2bf(glu1w[e2 * EMB + 2 * kp + 1]);
    g1p[i] = c0 | (c1 << 16);
  }

  float inv = 1.f / slen[b];

  // gather: group g loads rows l === g (mod 4); per-group partial sums
  float hsacc = 0.f, s0acc = 0.f;
  if (act) {
    for (int l = g; l < SEQ; l += 4) {
      int i1 = rsi[b * SEQ + l];
      float sv_ = (i1 > 0) ? item_hg[(i1 - 1) * EMB + e] : 0.f;
      seq[l * EMB + e] = sv_;
      hsacc += sv_;
      int i0 = si[b * SEQ + l];
      if (i0 > 0) s0acc += emb[(i0 - 1) * EMB + e];
    }
    hsP[g][e] = hsacc;
    s0P[g][e] = s0acc;
  }
  __syncthreads();
  if (act && g == 0) {
    float hv = (hsP[0][e] + hsP[1][e] + hsP[2][e] + hsP[3][e]) * inv;
    float sv = (s0P[0][e] + s0P[1][e] + s0P[2][e] + s0P[3][e]) * inv;
    hsL[e] = hv;
    X[b * EMB + e] = sv;
    Z[b * EMB + e] = sv;
  }
  __syncthreads();

  // hsgv[e] = glu1b[e] + sum_k hsL[k]*glu2w[e*EMB+k], k split across groups
  if (act) {
    float a = 0.f;
    int k0 = g * 25;
    for (int k = k0; k < k0 + 25; ++k) a += hsL[k] * glu2w[e * EMB + k];
    hsgP[g][e] = a;
  }
  __syncthreads();
  float hsgv = 0.f, w2v = 0.f;
  if (act) {
    hsgv = glu1b[e] + hsgP[0][e] + hsgP[1][e] + hsgP[2][e] + hsgP[3][e];
    w2v = w2[e];
  }

  float acc = 0.f;
  for (int it = 0; it < (SEQ + 3) / 4; ++it) {
    int l = it * 4 + g;
    bool lv = l < SEQ;
    __syncthreads();
    if (act && lv) {
      const float4* sq4 = (const float4*)&seq[l * EMB];
      float a0 = 0.f, a1 = 0.f, a2 = 0.f, a3 = 0.f;
      #pragma unroll
      for (int i = 0; i < 25; ++i) {
        float4 sv = sq4[i];
        unsigned int p0 = w1p[(2 * i) * EMB + e];
        unsigned int p1 = w1p[(2 * i + 1) * EMB + e];
        a0 += sv.x * lo2f(p0);
        a1 += sv.y * hi2f(p0);
        a2 += sv.z * lo2f(p1);
        a3 += sv.w * hi2f(p1);
      }
      float nh = posW[l * EMB + e] + ((a0 + a1) + (a2 + a3));
      nhL[g][e] = tanhf(nh);
    }
    __syncthreads();
    float p = 0.f;
    if (act && lv) {
      const float4* nq4 = (const float4*)nhL[g];
      float a0 = hsgv, a1 = 0.f, a2 = 0.f, a3 = 0.f;
      #pragma unroll
      for (int i = 0; i < 25; ++i) {
        float4 nv = nq4[i];
        unsigned int p0 = g1p[(2 * i) * EMB + e];
        unsigned int p1 = g1p[(2 * i + 1) * EMB + e];
        a0 += nv.x * lo2f(p0);
        a1 += nv.y * hi2f(p0);
        a2 += nv.z * lo2f(p1);
        a3 += nv.w * hi2f(p1);
      }
      float a = (a0 + a1) + (a2 + a3);
      float gs = 1.f / (1.f + __expf(-a));
      p = gs * w2v;
    }
    for (int off = 32; off; off >>= 1) p += __shfl_down(p, off, 64);
    if ((t & 63) == 0) redg[g][(t >> 6) & 1] = p;
    __syncthreads();
    if (act && lv) {
      float att = (redg[g][0] + redg[g][1]) * maskp[b * SEQ + l];
      acc += att * seq[l * EMB + e];
    }
  }
  if (act) accP[g][e] = acc;
  __syncthreads();
  if (act && g == 0)
    out_sess[b * EMB + e] = accP[0][e] + accP[1][e] + accP[2][e] + accP[3][e];
}

// ---------------- LineConv mat-vec: y = M @ x (all f32), optional Z += y ----------------
__global__ void mv_kernel(const float* __restrict__ M, const float* __restrict__ x,
                          float* __restrict__ y, float* __restrict__ Zacc) {
  __shared__ float Ms[BATCH];
  int b = blockIdx.x, t = threadIdx.x;
  for (int i = t; i < BATCH; i += 128) Ms[i] = M[b * BATCH + i];
  __syncthreads();
  if (t < EMB) {
    float a = 0.f;
    for (int k = 0; k < BATCH; ++k) a += Ms[k] * x[k * EMB + t];
    y[b * EMB + t] = a;
    if (Zacc) Zacc[b * EMB + t] += a;
  }
}

// ---------------- SSL loss: scaled atomicAdd straight into out_loss ----------------
__global__ void ssl_kernel(const float* __restrict__ Z, const float* __restrict__ hg,
                           const int* __restrict__ pr, const int* __restrict__ pc,
                           float* __restrict__ loss_out) {
  __shared__ float r1[128], r2[128];
  int b = blockIdx.x, t = threadIdx.x;
  float p1 = 0.f, p2 = 0.f;
  if (t < EMB) {
    float lg = Z[b * EMB + t];
    p1 = lg * hg[b * EMB + t];
    p2 = lg * hg[pr[b] * EMB + pc[t]];
  }
  r1[t] = p1; r2[t] = p2;
  __syncthreads();
  for (int off = 64; off; off >>= 1) {
    if (t < off) { r1[t] += r1[t + off]; r2[t] += r2[t + off]; }
    __syncthreads();
  }
  if (t == 0) {
    float sp = 1.f / (1.f + expf(-r1[0]));
    float sn = 1.f / (1.f + expf(-r2[0]));
    atomicAdd(loss_out, 0.01f * (-logf(1e-8f + sp) - logf(1e-8f + (1.f - sn))));
  }
}

extern "C" void kernel_launch(void* const* d_in, const int* in_sizes, int n_in,
                              void* d_out, int out_size, void* d_ws, size_t ws_size,
                              hipStream_t stream) {
  const int*   session_item = (const int*)d_in[0];
  const float* slen   = (const float*)d_in[1];
  const float* D      = (const float*)d_in[2];
  const float* A      = (const float*)d_in[3];
  const int*   rsi    = (const int*)d_in[4];
  const float* mask   = (const float*)d_in[5];
  const float* emb    = (const float*)d_in[6];
  const float* posw   = (const float*)d_in[7];
  const float* w1     = (const float*)d_in[8];
  const float* w2     = (const float*)d_in[9];
  const float* glu1w  = (const float*)d_in[10];
  const float* glu1b  = (const float*)d_in[11];
  const float* glu2w  = (const float*)d_in[12];
  const int*   adj_rows = (const int*)d_in[13];
  const int*   adj_cols = (const int*)d_in[14];
  const float* adj_vals = (const float*)d_in[15];
  const int*   pr     = (const int*)d_in[16];
  const int*   pc     = (const int*)d_in[17];

  // f32 OUTPUT layout: item [0,1e7), sess [1e7,1e7+51200), loss [+51200]
  float* out_item = (float*)d_out;
  float* out_sess = out_item + (size_t)N_NODE * EMB;
  float* out_loss = out_sess + (size_t)BATCH * EMB;
  float2* out2    = (float2*)d_out;
  const float2* emb2 = (const float2*)emb;

  char* ws = (char*)d_ws;
  size_t off = 0;
  auto alloc = [&](size_t bytes) -> void* {
    void* p = ws + off;
    off = (off + bytes + 255) & ~(size_t)255;
    return p;
  };

  hipMemsetAsync(out_loss, 0, 4, stream);

  if (ws_size >= 25500000) {
    // ===== TIER A+ (~25.5 MB): packed u32 CSR + bf16 in-place gather table =====
    int*          counts  = (int*)alloc((size_t)N_NODE * 4);
    int*          row_ptr = (int*)alloc((size_t)(N_NODE + 1) * 4);
    int*          partial = (int*)alloc((size_t)SCAN_NB * 4);
    unsigned int* cv      = (unsigned int*)alloc((size_t)NNZ * 4);
    unsigned int* ebf     = (unsigned int*)alloc((size_t)N_NODE * 50 * 4);  // 20 MB
    float* posW = (float*)alloc((size_t)SEQ * EMB * 4);
    float* X    = (float*)alloc((size_t)BATCH * EMB * 4);
    float* Y    = (float*)alloc((size_t)BATCH * EMB * 4);
    float* Z    = (float*)alloc((size_t)BATCH * EMB * 4);

    hipMemsetAsync(counts, 0, (size_t)N_NODE * 4, stream);

    // fused: histogram (atomic-bound) overlapped with bf16 table pack (streaming)
    hist_packbf_kernel<<<HIST_NB + PACK_NB, 256, 0, stream>>>(adj_rows, counts, emb2, ebf);
    scan_partial_kernel<<<SCAN_NB, 256, 0, stream>>>(counts, partial);
    scan_top_kernel<<<1, 128, 0, stream>>>(partial, row_ptr);
    scan_final_kernel<<<SCAN_NB, 256, 0, stream>>>(partial, counts, row_ptr);
    scatterA_kernel<<<(NNZ + 255) / 256, 256, 0, stream>>>(adj_rows, adj_cols, adj_vals,
                                                           counts, cv);
    spmmP1_kernel<<<N_NODE / 4, 256, 0, stream>>>(row_ptr, cv, emb2, ebf);
    spmmP2_kernel<<<N_NODE / 4, 256, 0, stream>>>(row_ptr, cv, ebf, emb2, out2);

    posw_kernel<<<SEQ, 128, 0, stream>>>(posw, w1, posW);
    sess_kernel<<<BATCH, 512, 0, stream>>>(rsi, session_item, out_item, emb, slen, posW,
                                           w1, glu1w, glu1b, glu2w, w2, mask,
                                           X, Z, out_sess);
    mv_kernel<<<BATCH, 128, 0, stream>>>(A, X, Y, (float*)nullptr);
    mv_kernel<<<BATCH, 128, 0, stream>>>(D, Y, X, Z);
    mv_kernel<<<BATCH, 128, 0, stream>>>(A, X, Y, (float*)nullptr);
    mv_kernel<<<BATCH, 128, 0, stream>>>(D, Y, X, Z);
    ssl_kernel<<<BATCH, 128, 0, stream>>>(Z, out_sess, pr, pc, out_loss);
  } else if (ws_size >= 5600000) {
    // ===== TIER A (~5.5 MB): packed u32 CSR, f32 gathers =====
    int*          counts  = (int*)alloc((size_t)N_NODE * 4);
    int*          row_ptr = (int*)alloc((size_t)(N_NODE + 1) * 4);
    int*          partial = (int*)alloc((size_t)SCAN_NB * 4);
    unsigned int* cv      = (unsigned int*)alloc((size_t)NNZ * 4);
    float* posW = (float*)alloc((size_t)SEQ * EMB * 4);
    float* X    = (float*)alloc((size_t)BATCH * EMB * 4);
    float* Y    = (float*)alloc((size_t)BATCH * EMB * 4);
    float* Z    = (float*)alloc((size_t)BATCH * EMB * 4);

    hipMemsetAsync(counts, 0, (size_t)N_NODE * 4, stream);

    hist_kernel<<<(NNZ + 255) / 256, 256, 0, stream>>>(adj_rows, counts);
    scan_partial_kernel<<<SCAN_NB, 256, 0, stream>>>(counts, partial);
    scan_top_kernel<<<1, 128, 0, stream>>>(partial, row_ptr);
    scan_final_kernel<<<SCAN_NB, 256, 0, stream>>>(partial, counts, row_ptr);
    scatterA_kernel<<<(NNZ + 255) / 256, 256, 0, stream>>>(adj_rows, adj_cols, adj_vals,
                                                           counts, cv);
    spmmA_kernel<<<N_NODE / 4, 256, 0, stream>>>(row_ptr, cv, emb2, emb2, out2);
    spmmA_kernel<<<N_NODE / 4, 256, 0, stream>>>(row_ptr, cv, out2, emb2, out2);

    posw_kernel<<<SEQ, 128, 0, stream>>>(posw, w1, posW);
    sess_kernel<<<BATCH, 512, 0, stream>>>(rsi, session_item, out_item, emb, slen, posW,
                                           w1, glu1w, glu1b, glu2w, w2, mask,
                                           X, Z, out_sess);
    mv_kernel<<<BATCH, 128, 0, stream>>>(A, X, Y, (float*)nullptr);
    mv_kernel<<<BATCH, 128, 0, stream>>>(D, Y, X, Z);
    mv_kernel<<<BATCH, 128, 0, stream>>>(A, X, Y, (float*)nullptr);
    mv_kernel<<<BATCH, 128, 0, stream>>>(D, Y, X, Z);
    ssl_kernel<<<BATCH, 128, 0, stream>>>(Z, out_sess, pr, pc, out_loss);
  } else {
    // ===== TIER B (~4.04 MB): 3-byte CSR; counts unioned with session scratch =====
    unsigned short* colHi  = (unsigned short*)alloc((size_t)NNZ * 2);   // 2.0 MB
    unsigned char*  colLo  = (unsigned char*)alloc((size_t)NNZ);        // 1.0 MB
    int*            row_ptr = (int*)alloc((size_t)(N_NODE + 1) * 4);    // 0.4 MB
    int*            partial = (int*)alloc((size_t)SCAN_NB * 4);         // 0.4 KB
    size_t u0 = off;
    int*   counts = (int*)alloc((size_t)N_NODE * 4);                    // 0.4 MB
    off = u0;  // union: session scratch overlays counts (dead after scatter)
    float* posW = (float*)alloc((size_t)SEQ * EMB * 4);
    float* X    = (float*)alloc((size_t)BATCH * EMB * 4);
    float* Y    = (float*)alloc((size_t)BATCH * EMB * 4);
    float* Z    = (float*)alloc((size_t)BATCH * EMB * 4);

    hipMemsetAsync(counts, 0, (size_t)N_NODE * 4, stream);

    hist_kernel<<<(NNZ + 255) / 256, 256, 0, stream>>>(adj_rows, counts);
    scan_partial_kernel<<<SCAN_NB, 256, 0, stream>>>(counts, partial);
    scan_top_kernel<<<1, 128, 0, stream>>>(partial, row_ptr);
    scan_final_kernel<<<SCAN_NB, 256, 0, stream>>>(partial, counts, row_ptr);
    scatterB_kernel<<<(NNZ + 255) / 256, 256, 0, stream>>>(adj_rows, adj_cols, adj_vals,
                                                           counts, colHi, colLo);
    spmmB_kernel<<<N_NODE / 4, 256, 0, stream>>>(row_ptr, colHi, colLo, emb2, emb2, out2);
    spmmB_kernel<<<N_NODE / 4, 256, 0, stream>>>(row_ptr, colHi, colLo, out2, emb2, out2);

    posw_kernel<<<SEQ, 128, 0, stream>>>(posw, w1, posW);
    sess_kernel<<<BATCH, 512, 0, stream>>>(rsi, session_item, out_item, emb, slen, posW,
                                           w1, glu1w, glu1b, glu2w, w2, mask,
                                           X, Z, out_sess);
    mv_kernel<<<BATCH, 128, 0, stream>>>(A, X, Y, (float*)nullptr);
    mv_kernel<<<BATCH, 128, 0, stream>>>(D, Y, X, Z);
    mv_kernel<<<BATCH, 128, 0, stream>>>(A, X, Y, (float*)nullptr);
    mv_kernel<<<BATCH, 128, 0, stream>>>(D, Y, X, Z);
    ssl_kernel<<<BATCH, 128, 0, stream>>>(Z, out_sess, pr, pc, out_loss);
  }
}